// Round 2
// baseline (382.874 us; speedup 1.0000x reference)
//
#include <hip/hip_runtime.h>
#include <hip/hip_bf16.h>
#include <cstdint>
#include <cstddef>

// Problem constants (fixed by reference)
#define BB 32
#define NN 8192
#define DIN 64
#define DOUT 128
#define NR 4
#define BN_EPS 1e-5f

typedef float nfloat4 __attribute__((ext_vector_type(4)));
typedef float floatx4 __attribute__((ext_vector_type(4)));
typedef short short8 __attribute__((ext_vector_type(8)));

// Workspace: [0, 64KB) uint smax_keys[B*NR*128]
// (memset 0 each launch; key 0 decodes below any real value's key)

__device__ inline void pack2(float a, float b, short8& dst, int idx) {
  // packed f32x2 -> bf16x2 (compiler emits v_cvt_pk_bf16_f32 on gfx950)
  __hip_bfloat162 h = __float22bfloat162_rn(make_float2(a, b));
  const unsigned int bits = *(unsigned int*)&h;
  dst[idx] = (short)(bits & 0xffffu);
  dst[idx + 1] = (short)(bits >> 16);
}

// ---------------------------------------------------------------------------
// K1 (MFMA, direct-global, no LDS): block = (b, 128-point chunk), 4 waves.
// Wave w owns channel tiles {w, w+4} (32 chans). B-fragments load DIRECTLY
// from x's native [d][n] layout: lane(l16,quad) reads x[quad*8+j][n] -- each
// 16-lane group covers 16 consecutive n = 64B lines, fully coalesced,
// L2/L3-served after iteration 1. 2048 blocks (8/CU) + a hand-written
// two-stage software pipeline (named buffers, static indices only) keep
// ~17 loads in flight per wave while pack+MFMA runs -- this kernel is
// latency-bound, not BW-bound (FETCH ~34MB but dur 80us in r0).
// Per-ring segment max via register masks (ring==r ? v : -inf), 16-point
// butterfly, one atomicMax per (ring, chan).
__global__ void __launch_bounds__(256, 3) k_compute(
    const float* __restrict__ x, const float* __restrict__ W,
    const int* __restrict__ ring, unsigned int* __restrict__ smax_keys) {
  const int b = blockIdx.y;
  const int n0 = blockIdx.x * 128;  // 128-pt chunk -> T = 8 sub-tiles of 16
  const int wave = (int)threadIdx.x >> 6;
  const int lane = (int)threadIdx.x & 63;
  const int quad = lane >> 4;
  const int l16 = lane & 15;
  const float* xb = x + (size_t)b * DIN * NN;
  const int* rgb = ring + (size_t)b * NN;

  // A fragments for all 4 rings: afr[r][tile][kstep], A[m=l16][k=quad*8+j].
  // 4r x 2t x 2ks x 4 VGPR = 64 VGPR of bf16 W data (tiny, L1/L2-served).
  short8 afr[NR][2][2];
#pragma unroll
  for (int r = 0; r < NR; ++r) {
#pragma unroll
    for (int tt = 0; tt < 2; ++tt) {
      const int chan = (wave + 4 * tt) * 16 + l16;
      const float* wr = W + ((size_t)r * DOUT + chan) * DIN + quad * 8;
#pragma unroll
      for (int ks = 0; ks < 2; ++ks) {
        const float4 w0 = *(const float4*)&wr[ks * 32];
        const float4 w1 = *(const float4*)&wr[ks * 32 + 4];
        short8 a;
        pack2(w0.x, w0.y, a, 0);
        pack2(w0.z, w0.w, a, 2);
        pack2(w1.x, w1.y, a, 4);
        pack2(w1.z, w1.w, a, 6);
        afr[r][tt][ks] = a;
      }
    }
  }

  floatx4 rmax[2][NR];
#pragma unroll
  for (int tt = 0; tt < 2; ++tt)
#pragma unroll
    for (int r = 0; r < NR; ++r)
      rmax[tt][r] = {-INFINITY, -INFINITY, -INFINITY, -INFINITY};

  // Two named pipeline buffers (NO runtime indexing -> stays in VGPRs).
  float pA[16], pB[16];
  int rA, rB;

  // issue the 16 x-loads + 1 ring load for sub-tile T
  auto LD = [&](float (&buf)[16], int& rr, int T) {
    const int n = n0 + T * 16 + l16;
#pragma unroll
    for (int j = 0; j < 8; ++j) {
      buf[j] = xb[(size_t)(quad * 8 + j) * NN + n];
      buf[8 + j] = xb[(size_t)(32 + quad * 8 + j) * NN + n];
    }
    rr = rgb[n];
  };

  // pack to bf16 fragments, 16 MFMA (4 rings x 2 tiles x 2 ksteps),
  // masked running max
  auto CMP = [&](const float (&buf)[16], int rr) {
    short8 b0, b1;
#pragma unroll
    for (int j = 0; j < 4; ++j) {
      pack2(buf[2 * j], buf[2 * j + 1], b0, 2 * j);
      pack2(buf[8 + 2 * j], buf[8 + 2 * j + 1], b1, 2 * j);
    }
#pragma unroll
    for (int r = 0; r < NR; ++r) {
      floatx4 acc0 = {0.f, 0.f, 0.f, 0.f};
      floatx4 acc1 = {0.f, 0.f, 0.f, 0.f};
      acc0 = __builtin_amdgcn_mfma_f32_16x16x32_bf16(afr[r][0][0], b0, acc0, 0, 0, 0);
      acc0 = __builtin_amdgcn_mfma_f32_16x16x32_bf16(afr[r][0][1], b1, acc0, 0, 0, 0);
      acc1 = __builtin_amdgcn_mfma_f32_16x16x32_bf16(afr[r][1][0], b0, acc1, 0, 0, 0);
      acc1 = __builtin_amdgcn_mfma_f32_16x16x32_bf16(afr[r][1][1], b1, acc1, 0, 0, 0);
      const bool m = (rr == r);
#pragma unroll
      for (int p = 0; p < 4; ++p) {
        rmax[0][r][p] = fmaxf(rmax[0][r][p], m ? acc0[p] : -INFINITY);
        rmax[1][r][p] = fmaxf(rmax[1][r][p], m ? acc1[p] : -INFINITY);
      }
    }
  };

  // software pipeline: loads for T+1 are in flight while T computes
  LD(pA, rA, 0);
#pragma unroll 1
  for (int T = 0; T < 8; T += 2) {
    LD(pB, rB, T + 1);
    CMP(pA, rA);
    if (T + 2 < 8) LD(pA, rA, T + 2);
    CMP(pB, rB);
  }

  // reduce over the 16 point-columns (lane bits 0-3); one atomic per
  // (ring, chan) from the l16==0 lane of each quad.
#pragma unroll
  for (int tt = 0; tt < 2; ++tt) {
#pragma unroll
    for (int r = 0; r < NR; ++r) {
#pragma unroll
      for (int p = 0; p < 4; ++p) {
        float v = rmax[tt][r][p];
        v = fmaxf(v, __shfl_xor(v, 1, 64));
        v = fmaxf(v, __shfl_xor(v, 2, 64));
        v = fmaxf(v, __shfl_xor(v, 4, 64));
        v = fmaxf(v, __shfl_xor(v, 8, 64));
        if (l16 == 0) {
          const int chan = (wave + 4 * tt) * 16 + quad * 4 + p;
          const unsigned int u = __float_as_uint(v);
          const unsigned int key = (u & 0x80000000u) ? ~u : (u | 0x80000000u);
          atomicMax(&smax_keys[(size_t)(b * NR + r) * DOUT + chan], key);
        }
      }
    }
  }
}

// ---------------------------------------------------------------------------
// K2: finalize affine on the 16K maxima, then broadcast to output:
// out[b][o][n] = ymax[b][ring[b,n]][o].
// Restructured for write locality: block = (b, group of 4 consecutive
// channels); wave w streams channel o = og*4+w's ENTIRE 32KB row
// sequentially (old layout wrote scattered 4KB bursts at 32KB stride ->
// ~2 TB/s). The 4-entry ring LUT is 4 wave-uniform scalars in VGPRs
// (no LDS, no gather); selection = 3 cndmask per output float with the
// v_cmp masks shared across the float4.
__global__ void __launch_bounds__(256) k_out(
    const float* __restrict__ bias, const float* __restrict__ gamma,
    const float* __restrict__ beta, const float* __restrict__ mean,
    const float* __restrict__ var, const int* __restrict__ ring,
    const unsigned int* __restrict__ smax_keys, float* __restrict__ out) {
  const int b = blockIdx.y;
  const int og = blockIdx.x;  // 32 groups of 4 consecutive channels
  const int wave = (int)threadIdx.x >> 6;
  const int lane = (int)threadIdx.x & 63;
  const int o = og * 4 + wave;

  // per-wave uniform 4-entry LUT (one float per ring)
  float yv0, yv1, yv2, yv3;
  {
    float tmp[NR];
#pragma unroll
    for (int r = 0; r < NR; ++r) {
      const int t = r * DOUT + o;
      const unsigned int key = smax_keys[(size_t)b * NR * DOUT + t];
      const unsigned int u = (key & 0x80000000u) ? (key ^ 0x80000000u) : ~key;
      const float raw = __uint_as_float(u);
      const float sc = gamma[t] * rsqrtf(var[t] + BN_EPS);
      tmp[r] = (raw + bias[t] - mean[t]) * sc + beta[t];
    }
    yv0 = tmp[0]; yv1 = tmp[1]; yv2 = tmp[2]; yv3 = tmp[3];
  }

  const int* rgb = ring + (size_t)b * NN;
  float* orow = out + ((size_t)b * DOUT + o) * NN;

#pragma unroll 4
  for (int it = 0; it < NN / 256; ++it) {
    const int n = it * 256 + lane * 4;
    const int4 rg = *(const int4*)&rgb[n];
    nfloat4 v;
    { float lo = (rg.x & 1) ? yv1 : yv0, hi = (rg.x & 1) ? yv3 : yv2;
      v.x = (rg.x & 2) ? hi : lo; }
    { float lo = (rg.y & 1) ? yv1 : yv0, hi = (rg.y & 1) ? yv3 : yv2;
      v.y = (rg.y & 2) ? hi : lo; }
    { float lo = (rg.z & 1) ? yv1 : yv0, hi = (rg.z & 1) ? yv3 : yv2;
      v.z = (rg.z & 2) ? hi : lo; }
    { float lo = (rg.w & 1) ? yv1 : yv0, hi = (rg.w & 1) ? yv3 : yv2;
      v.w = (rg.w & 2) ? hi : lo; }
    __builtin_nontemporal_store(v, (nfloat4*)(orow + n));
  }
}

// ---------------------------------------------------------------------------
extern "C" void kernel_launch(void* const* d_in, const int* in_sizes, int n_in,
                              void* d_out, int out_size, void* d_ws, size_t ws_size,
                              hipStream_t stream) {
  const float* x = (const float*)d_in[0];
  const int* ring = (const int*)d_in[1];
  const float* W = (const float*)d_in[2];
  const float* bias = (const float*)d_in[3];
  const float* gamma = (const float*)d_in[4];
  const float* beta = (const float*)d_in[5];
  const float* mean = (const float*)d_in[6];
  const float* var = (const float*)d_in[7];
  float* out = (float*)d_out;

  unsigned int* keys = (unsigned int*)d_ws;

  // zero smax keys (key 0 decodes below every real key)
  (void)hipMemsetAsync(keys, 0, (size_t)BB * NR * DOUT * 4, stream);

  k_compute<<<dim3(NN / 128, BB), 256, 0, stream>>>(x, W, ring, keys);
  k_out<<<dim3(DOUT / 4, BB), 256, 0, stream>>>(bias, gamma, beta, mean,
                                                var, ring, keys, out);
}

// Round 3
// 230.267 us; speedup vs baseline: 1.6627x; 1.6627x over previous
//
#include <hip/hip_runtime.h>
#include <hip/hip_bf16.h>
#include <cstdint>
#include <cstddef>

// Problem constants (fixed by reference)
#define BB 32
#define NN 8192
#define DIN 64
#define DOUT 128
#define NR 4
#define BN_EPS 1e-5f

typedef float nfloat4 __attribute__((ext_vector_type(4)));
typedef float floatx4 __attribute__((ext_vector_type(4)));
typedef short short8 __attribute__((ext_vector_type(8)));

// Workspace: [0, 64KB) uint smax_keys[B*NR*128]
// (memset 0 each launch; key 0 decodes below any real value's key)

__device__ inline void pack2(float a, float b, short8& dst, int idx) {
  // packed f32x2 -> bf16x2 (compiler emits v_cvt_pk_bf16_f32 on gfx950)
  __hip_bfloat162 h = __float22bfloat162_rn(make_float2(a, b));
  const unsigned int bits = *(unsigned int*)&h;
  dst[idx] = (short)(bits & 0xffffu);
  dst[idx + 1] = (short)(bits >> 16);
}

// ---------------------------------------------------------------------------
// K1 (MFMA, direct-global, r0 grid): block = (b, 256-point chunk), 4 waves.
// Wave w owns channel tiles {w, w+4} (32 chans). B-fragments load DIRECTLY
// from x's native [d][n] layout: lane(l16,quad) reads x[quad*8+j][n] -- each
// 16-lane group covers 16 consecutive n = full 64B lines, fully coalesced.
// NEW vs r0: zero-register software rotate -- pack(T) frees the load buffer,
// then T+1's 17 loads are issued BEFORE T's ~600-cycle MFMA+mask block, so
// the L2/L3 latency (~1000cy exposed in r0, 31% VALUBusy) hides under
// compute. Grid kept at 1024 blocks (r2 showed 2048 blocks thrashes L2/L3:
// FETCH 34->195MB). Per-ring segment max via register masks, 16-pt
// butterfly, one atomicMax per (ring, chan).
__global__ void __launch_bounds__(256) k_compute(
    const float* __restrict__ x, const float* __restrict__ W,
    const int* __restrict__ ring, unsigned int* __restrict__ smax_keys) {
  const int b = blockIdx.y;
  const int n0 = blockIdx.x * 256;
  const int wave = (int)threadIdx.x >> 6;
  const int lane = (int)threadIdx.x & 63;
  const int quad = lane >> 4;
  const int l16 = lane & 15;
  const float* xb = x + (size_t)b * DIN * NN;
  const int* rgb = ring + (size_t)b * NN;

  // A fragments for all 4 rings: afr[r][tile][kstep], A[m=l16][k=quad*8+j].
  short8 afr[NR][2][2];
#pragma unroll
  for (int r = 0; r < NR; ++r) {
#pragma unroll
    for (int tt = 0; tt < 2; ++tt) {
      const int chan = (wave + 4 * tt) * 16 + l16;
      const float* wr = W + ((size_t)r * DOUT + chan) * DIN + quad * 8;
#pragma unroll
      for (int ks = 0; ks < 2; ++ks) {
        const float4 w0 = *(const float4*)&wr[ks * 32];
        const float4 w1 = *(const float4*)&wr[ks * 32 + 4];
        short8 a;
        pack2(w0.x, w0.y, a, 0);
        pack2(w0.z, w0.w, a, 2);
        pack2(w1.x, w1.y, a, 4);
        pack2(w1.z, w1.w, a, 6);
        afr[r][tt][ks] = a;
      }
    }
  }

  floatx4 rmax[2][NR];
#pragma unroll
  for (int tt = 0; tt < 2; ++tt)
#pragma unroll
    for (int r = 0; r < NR; ++r)
      rmax[tt][r] = {-INFINITY, -INFINITY, -INFINITY, -INFINITY};

  // single rotating load buffer (freed by pack, refilled for T+1)
  float bx[16];
  int rn;
  auto LD = [&](int T) {
    const int n = n0 + T * 16 + l16;
#pragma unroll
    for (int j = 0; j < 8; ++j) {
      bx[j] = xb[(size_t)(quad * 8 + j) * NN + n];
      bx[8 + j] = xb[(size_t)(32 + quad * 8 + j) * NN + n];
    }
    rn = rgb[n];
  };

  LD(0);
#pragma unroll 1
  for (int T = 0; T < 16; ++T) {
    // pack consumes bx (waits on the loads issued one MFMA-block ago)
    short8 b0, b1;
#pragma unroll
    for (int j = 0; j < 4; ++j) {
      pack2(bx[2 * j], bx[2 * j + 1], b0, 2 * j);
      pack2(bx[8 + 2 * j], bx[8 + 2 * j + 1], b1, 2 * j);
    }
    const int rr = rn;
    if (T < 15) LD(T + 1);  // issue next tile's loads; they fly during MFMA

#pragma unroll
    for (int r = 0; r < NR; ++r) {
      floatx4 acc0 = {0.f, 0.f, 0.f, 0.f};
      floatx4 acc1 = {0.f, 0.f, 0.f, 0.f};
      acc0 = __builtin_amdgcn_mfma_f32_16x16x32_bf16(afr[r][0][0], b0, acc0, 0, 0, 0);
      acc0 = __builtin_amdgcn_mfma_f32_16x16x32_bf16(afr[r][0][1], b1, acc0, 0, 0, 0);
      acc1 = __builtin_amdgcn_mfma_f32_16x16x32_bf16(afr[r][1][0], b0, acc1, 0, 0, 0);
      acc1 = __builtin_amdgcn_mfma_f32_16x16x32_bf16(afr[r][1][1], b1, acc1, 0, 0, 0);
      const bool m = (rr == r);
#pragma unroll
      for (int p = 0; p < 4; ++p) {
        rmax[0][r][p] = fmaxf(rmax[0][r][p], m ? acc0[p] : -INFINITY);
        rmax[1][r][p] = fmaxf(rmax[1][r][p], m ? acc1[p] : -INFINITY);
      }
    }
  }

  // reduce over the 16 point-columns (lane bits 0-3); one atomic per
  // (ring, chan) from the l16==0 lane of each quad.
#pragma unroll
  for (int tt = 0; tt < 2; ++tt) {
#pragma unroll
    for (int r = 0; r < NR; ++r) {
#pragma unroll
      for (int p = 0; p < 4; ++p) {
        float v = rmax[tt][r][p];
        v = fmaxf(v, __shfl_xor(v, 1, 64));
        v = fmaxf(v, __shfl_xor(v, 2, 64));
        v = fmaxf(v, __shfl_xor(v, 4, 64));
        v = fmaxf(v, __shfl_xor(v, 8, 64));
        if (l16 == 0) {
          const int chan = (wave + 4 * tt) * 16 + quad * 4 + p;
          const unsigned int u = __float_as_uint(v);
          const unsigned int key = (u & 0x80000000u) ? ~u : (u | 0x80000000u);
          atomicMax(&smax_keys[(size_t)(b * NR + r) * DOUT + chan], key);
        }
      }
    }
  }
}

// ---------------------------------------------------------------------------
// K2: finalize affine on the 16K maxima, then broadcast to output:
// out[b][o][n] = ymax[b][ring[b,n]][o].  r0's grid/write pattern (the best
// measured: 69us) with its ONE defect fixed: the old gather ymax[oo*4+rg]
// put all 64 lanes in 4 banks (16-way conflict, ~27us of LDS serialization).
// The LUT is now replicated 32x: lut[oo][r][c], c = lane&31 -> per-lane
// address rg*32+(lane&31), bank = lane&31 REGARDLESS of ring: conflict-free.
// Inner loop = 4 ds_read_b32 (immediate oo*512 offsets, base regs loop-
// invariant) + 1 nontemporal float4 store. No VCC-serialized selects.
__global__ void __launch_bounds__(256) k_out(
    const float* __restrict__ bias, const float* __restrict__ gamma,
    const float* __restrict__ beta, const float* __restrict__ mean,
    const float* __restrict__ var, const int* __restrict__ ring,
    const unsigned int* __restrict__ smax_keys, float* __restrict__ out) {
  const int b = blockIdx.z;
  const int og = blockIdx.y;  // 32-channel group
  const int n0 = blockIdx.x * 1024;
  const int t = (int)threadIdx.x;

  __shared__ float lut[32 * NR * 32];  // [oo][r][c32], 16 KB
  {
    // thread t computes ONE (oo, r) value and writes 16 replicas
    const int oo = t >> 3;
    const int r = (t >> 1) & 3;
    const int c0 = (t & 1) * 16;
    const int o = og * 32 + oo;
    const int tt = r * DOUT + o;
    const unsigned int key = smax_keys[(size_t)b * NR * DOUT + tt];
    const unsigned int u = (key & 0x80000000u) ? (key ^ 0x80000000u) : ~key;
    const float raw = __uint_as_float(u);
    const float sc = gamma[tt] * rsqrtf(var[tt] + BN_EPS);
    const float val = (raw + bias[tt] - mean[tt]) * sc + beta[tt];
    nfloat4 v4 = {val, val, val, val};
    float* dst = &lut[(oo * NR + r) * 32 + c0];
#pragma unroll
    for (int k = 0; k < 4; ++k) *(nfloat4*)&dst[k * 4] = v4;
  }
  __syncthreads();

  const int n = n0 + t * 4;
  const int4 rg = *(const int4*)&ring[(size_t)b * NN + n];
  const int l31 = t & 31;
  // loop-invariant per-component gather bases (float index into lut)
  const float* p0 = &lut[rg.x * 32 + l31];
  const float* p1 = &lut[rg.y * 32 + l31];
  const float* p2 = &lut[rg.z * 32 + l31];
  const float* p3 = &lut[rg.w * 32 + l31];
  float* orow = out + ((size_t)b * DOUT + og * 32) * NN + n;

#pragma unroll 8
  for (int oo = 0; oo < 32; ++oo) {
    nfloat4 v;
    v.x = p0[oo * 128];  // ds_read_b32 ... offset:oo*512, conflict-free
    v.y = p1[oo * 128];
    v.z = p2[oo * 128];
    v.w = p3[oo * 128];
    __builtin_nontemporal_store(v, (nfloat4*)(orow + (size_t)oo * NN));
  }
}

// ---------------------------------------------------------------------------
extern "C" void kernel_launch(void* const* d_in, const int* in_sizes, int n_in,
                              void* d_out, int out_size, void* d_ws, size_t ws_size,
                              hipStream_t stream) {
  const float* x = (const float*)d_in[0];
  const int* ring = (const int*)d_in[1];
  const float* W = (const float*)d_in[2];
  const float* bias = (const float*)d_in[3];
  const float* gamma = (const float*)d_in[4];
  const float* beta = (const float*)d_in[5];
  const float* mean = (const float*)d_in[6];
  const float* var = (const float*)d_in[7];
  float* out = (float*)d_out;

  unsigned int* keys = (unsigned int*)d_ws;

  // zero smax keys (key 0 decodes below every real key)
  (void)hipMemsetAsync(keys, 0, (size_t)BB * NR * DOUT * 4, stream);

  k_compute<<<dim3(NN / 256, BB), 256, 0, stream>>>(x, W, ring, keys);
  k_out<<<dim3(NN / 1024, DOUT / 32, BB), 256, 0, stream>>>(bias, gamma, beta, mean,
                                                            var, ring, keys, out);
}

// Round 4
// 228.225 us; speedup vs baseline: 1.6776x; 1.0089x over previous
//
#include <hip/hip_runtime.h>
#include <hip/hip_bf16.h>
#include <cstdint>
#include <cstddef>

// Problem constants (fixed by reference)
#define BB 32
#define NN 8192
#define DIN 64
#define DOUT 128
#define NR 4
#define BN_EPS 1e-5f

typedef float nfloat4 __attribute__((ext_vector_type(4)));
typedef float floatx4 __attribute__((ext_vector_type(4)));
typedef short short8 __attribute__((ext_vector_type(8)));

// Workspace: [0, 64KB) uint smax_keys[B*NR*128]
// (memset 0 each launch; key 0 decodes below any real value's key)

__device__ inline void pack2(float a, float b, short8& dst, int idx) {
  // packed f32x2 -> bf16x2 (compiler emits v_cvt_pk_bf16_f32 on gfx950)
  __hip_bfloat162 h = __float22bfloat162_rn(make_float2(a, b));
  const unsigned int bits = *(unsigned int*)&h;
  dst[idx] = (short)(bits & 0xffffu);
  dst[idx + 1] = (short)(bits >> 16);
}

// LDS 16B-group swizzle: distinct across any 8 consecutive lanes for BOTH
// the stage writes (n = 4*lane+i) and the fragment reads (n = T*16+l16).
// Verified on paper: all 8-lane subgroups map to 8 distinct 4-bank groups.
__device__ inline int swz(int n) { return (n ^ (n >> 2) ^ (n >> 5)) & 7; }

// ---------------------------------------------------------------------------
// K1 (MFMA): block = (b, 256-point chunk), 4 waves. Wave w owns channel
// tiles {w, w+4} (32 chans).
//
// r0-r3 lesson: the d-strided transpose-read of x (16 scalar dwords at 32KB
// stride per lane) runs at ~530 GB/s effective -- HBM/L3 request-inefficiency
// bound; in-wave prefetch doesn't help (r3 == r0). Fix: read x with the SAME
// pattern the 6.8 TB/s fill kernel uses -- each wave reads its 16 d-rows as
// 1KB-contiguous float4 bursts -- then transpose on-chip:
//   * d lives in the unroll dimension -> the 8x4 transpose is free register
//     renaming; convert to bf16 (pack moves out of the T loop);
//   * ds_write_b128 into [n][dblk^swz(n)] -- conflict-free writes AND reads;
//   * inner loop: per T just 2 x ds_read_b128 -> MFMA (vs 16 scalar global
//     loads + 8 cvt_pk in r0).
// Per-ring segment max via register masks, 16-pt butterfly, one atomicMax
// per (ring, chan).
__global__ void __launch_bounds__(256) k_compute(
    const float* __restrict__ x, const float* __restrict__ W,
    const int* __restrict__ ring, unsigned int* __restrict__ smax_keys) {
  const int b = blockIdx.y;
  const int n0 = blockIdx.x * 256;
  const int wave = (int)threadIdx.x >> 6;
  const int lane = (int)threadIdx.x & 63;
  const int quad = lane >> 4;
  const int l16 = lane & 15;
  const float* xb = x + (size_t)b * DIN * NN;
  const int* rgb = ring + (size_t)b * NN;

  // bf16 tile, [n=256][8 groups of 8 d], 16B units, XOR-swizzled: 32 KB
  __shared__ short8 lx[256 * 8];

  // ---- stage: wave w reads rows d = w*16 .. w*16+15 (1KB sequential per
  // row per wave-instr), in-register transpose, bf16 pack, swizzled write.
  {
    const float* xr = xb + (size_t)(wave * 16) * NN + n0 + 4 * lane;
#pragma unroll
    for (int grp = 0; grp < 2; ++grp) {
      nfloat4 L[8];
#pragma unroll
      for (int j = 0; j < 8; ++j)
        L[j] = *(const nfloat4*)&xr[(size_t)(grp * 8 + j) * NN];
#pragma unroll
      for (int i = 0; i < 4; ++i) {
        short8 v;
        pack2(L[0][i], L[1][i], v, 0);
        pack2(L[2][i], L[3][i], v, 2);
        pack2(L[4][i], L[5][i], v, 4);
        pack2(L[6][i], L[7][i], v, 6);
        const int ni = 4 * lane + i;  // point column within the tile
        lx[ni * 8 + ((wave * 2 + grp) ^ swz(ni))] = v;
      }
    }
  }

  // A fragments for all 4 rings: afr[r][tile][kstep], A[m=l16][k=quad*8+j].
  // 4r x 2t x 2ks x 4 VGPR = 64 VGPR of bf16 W data (tiny, L1/L2-served).
  short8 afr[NR][2][2];
#pragma unroll
  for (int r = 0; r < NR; ++r) {
#pragma unroll
    for (int tt = 0; tt < 2; ++tt) {
      const int chan = (wave + 4 * tt) * 16 + l16;
      const float* wr = W + ((size_t)r * DOUT + chan) * DIN + quad * 8;
#pragma unroll
      for (int ks = 0; ks < 2; ++ks) {
        const float4 w0 = *(const float4*)&wr[ks * 32];
        const float4 w1 = *(const float4*)&wr[ks * 32 + 4];
        short8 a;
        pack2(w0.x, w0.y, a, 0);
        pack2(w0.z, w0.w, a, 2);
        pack2(w1.x, w1.y, a, 4);
        pack2(w1.z, w1.w, a, 6);
        afr[r][tt][ks] = a;
      }
    }
  }

  floatx4 rmax[2][NR];
#pragma unroll
  for (int tt = 0; tt < 2; ++tt)
#pragma unroll
    for (int r = 0; r < NR; ++r)
      rmax[tt][r] = {-INFINITY, -INFINITY, -INFINITY, -INFINITY};

  __syncthreads();  // staged tile visible to all waves

#pragma unroll 4
  for (int T = 0; T < 16; ++T) {
    const int n = T * 16 + l16;
    const short8 b0 = lx[n * 8 + (quad ^ swz(n))];        // d = quad*8+j
    const short8 b1 = lx[n * 8 + ((4 + quad) ^ swz(n))];  // d = 32+quad*8+j
    const int rr = rgb[n0 + n];
#pragma unroll
    for (int r = 0; r < NR; ++r) {
      floatx4 acc0 = {0.f, 0.f, 0.f, 0.f};
      floatx4 acc1 = {0.f, 0.f, 0.f, 0.f};
      acc0 = __builtin_amdgcn_mfma_f32_16x16x32_bf16(afr[r][0][0], b0, acc0, 0, 0, 0);
      acc0 = __builtin_amdgcn_mfma_f32_16x16x32_bf16(afr[r][0][1], b1, acc0, 0, 0, 0);
      acc1 = __builtin_amdgcn_mfma_f32_16x16x32_bf16(afr[r][1][0], b0, acc1, 0, 0, 0);
      acc1 = __builtin_amdgcn_mfma_f32_16x16x32_bf16(afr[r][1][1], b1, acc1, 0, 0, 0);
      const bool m = (rr == r);
#pragma unroll
      for (int p = 0; p < 4; ++p) {
        rmax[0][r][p] = fmaxf(rmax[0][r][p], m ? acc0[p] : -INFINITY);
        rmax[1][r][p] = fmaxf(rmax[1][r][p], m ? acc1[p] : -INFINITY);
      }
    }
  }

  // reduce over the 16 point-columns (lane bits 0-3); one atomic per
  // (ring, chan) from the l16==0 lane of each quad.
#pragma unroll
  for (int tt = 0; tt < 2; ++tt) {
#pragma unroll
    for (int r = 0; r < NR; ++r) {
#pragma unroll
      for (int p = 0; p < 4; ++p) {
        float v = rmax[tt][r][p];
        v = fmaxf(v, __shfl_xor(v, 1, 64));
        v = fmaxf(v, __shfl_xor(v, 2, 64));
        v = fmaxf(v, __shfl_xor(v, 4, 64));
        v = fmaxf(v, __shfl_xor(v, 8, 64));
        if (l16 == 0) {
          const int chan = (wave + 4 * tt) * 16 + quad * 4 + p;
          const unsigned int u = __float_as_uint(v);
          const unsigned int key = (u & 0x80000000u) ? ~u : (u | 0x80000000u);
          atomicMax(&smax_keys[(size_t)(b * NR + r) * DOUT + chan], key);
        }
      }
    }
  }
}

// ---------------------------------------------------------------------------
// K2: finalize affine on the 16K maxima, broadcast to out[b][o][n] =
// ymax[b][ring[b,n]][o].
// r0 vs r1/r2 lesson: the serializer is DEPENDENT ring loads inside the
// store loop, not LDS conflicts. v4: block = (b, channel o, half-row) ->
// writes 16 KB contiguous; ALL 4 ring int4 loads hoisted up-front
// (independent, in flight together); 4-entry LUT in registers (per-block
// uniform); 3-cndmask select per output float. 8192 blocks for overlap.
__global__ void __launch_bounds__(256) k_out(
    const float* __restrict__ bias, const float* __restrict__ gamma,
    const float* __restrict__ beta, const float* __restrict__ mean,
    const float* __restrict__ var, const int* __restrict__ ring,
    const unsigned int* __restrict__ smax_keys, float* __restrict__ out) {
  const int b = blockIdx.z;
  const int o = blockIdx.y;   // channel
  const int nh = blockIdx.x;  // half-row
  const int t = (int)threadIdx.x;

  // per-block uniform 4-entry LUT (scalarizes; loads are broadcast L2 hits)
  auto fin = [&](int r) -> float {
    const int tt = r * DOUT + o;
    const unsigned int key = smax_keys[(size_t)b * NR * DOUT + tt];
    const unsigned int u = (key & 0x80000000u) ? (key ^ 0x80000000u) : ~key;
    const float raw = __uint_as_float(u);
    const float sc = gamma[tt] * rsqrtf(var[tt] + BN_EPS);
    return (raw + bias[tt] - mean[tt]) * sc + beta[tt];
  };
  const float yv0 = fin(0), yv1 = fin(1), yv2 = fin(2), yv3 = fin(3);

  const int base = nh * (NN / 2);
  const int* rgb = ring + (size_t)b * NN + base;
  float* orow = out + ((size_t)b * DOUT + o) * NN + base;

  // hoist all 4 independent ring int4 loads (no dependent load in the loop)
  int4 rg0 = *(const int4*)&rgb[0 * 1024 + t * 4];
  int4 rg1 = *(const int4*)&rgb[1 * 1024 + t * 4];
  int4 rg2 = *(const int4*)&rgb[2 * 1024 + t * 4];
  int4 rg3 = *(const int4*)&rgb[3 * 1024 + t * 4];

  auto sel = [&](int r) -> float {
    const float lo = (r & 1) ? yv1 : yv0;
    const float hi = (r & 1) ? yv3 : yv2;
    return (r & 2) ? hi : lo;
  };
  auto emit = [&](const int4& rg, int it) {
    nfloat4 v;
    v.x = sel(rg.x);
    v.y = sel(rg.y);
    v.z = sel(rg.z);
    v.w = sel(rg.w);
    __builtin_nontemporal_store(v, (nfloat4*)&orow[it * 1024 + t * 4]);
  };
  emit(rg0, 0);
  emit(rg1, 1);
  emit(rg2, 2);
  emit(rg3, 3);
}

// ---------------------------------------------------------------------------
extern "C" void kernel_launch(void* const* d_in, const int* in_sizes, int n_in,
                              void* d_out, int out_size, void* d_ws, size_t ws_size,
                              hipStream_t stream) {
  const float* x = (const float*)d_in[0];
  const int* ring = (const int*)d_in[1];
  const float* W = (const float*)d_in[2];
  const float* bias = (const float*)d_in[3];
  const float* gamma = (const float*)d_in[4];
  const float* beta = (const float*)d_in[5];
  const float* mean = (const float*)d_in[6];
  const float* var = (const float*)d_in[7];
  float* out = (float*)d_out;

  unsigned int* keys = (unsigned int*)d_ws;

  // zero smax keys (key 0 decodes below every real key)
  (void)hipMemsetAsync(keys, 0, (size_t)BB * NR * DOUT * 4, stream);

  k_compute<<<dim3(NN / 256, BB), 256, 0, stream>>>(x, W, ring, keys);
  k_out<<<dim3(2, DOUT, BB), 256, 0, stream>>>(bias, gamma, beta, mean,
                                               var, ring, keys, out);
}